// Round 1
// baseline (269.257 us; speedup 1.0000x reference)
//
#include <hip/hip_runtime.h>
#include <cstdint>

typedef __bf16 bf16_t;
typedef __attribute__((ext_vector_type(8))) __bf16 bf16x8;
typedef __attribute__((ext_vector_type(4))) __bf16 bf16x4;
typedef __attribute__((ext_vector_type(4))) float f32x4;

#define AS1 __attribute__((address_space(1)))
#define AS3 __attribute__((address_space(3)))

// ---------------------------------------------------------------------------
// Big-tile NT bf16 GEMM: C[m,n] = sum_k A[m*lda+k] * B[n*ldb+k]
// Tile 128x128, BK=64, 256 threads, DOUBLE-BUFFERED LDS (64KB, 2 blocks/CU).
// One barrier/iter; prefetch for tile k+1 issued right after it. 717 TF
// measured (round 7, step 3). DO NOT merge multiple operand sets into this
// kernel (round 8: VGPR 88->132, MfmaUtil 28->20.5, -33% perf).
//
// LDS layout: rows of 8 16B-chunks, chunk q of row r at slot q ^ (r&7)
// (XOR swizzle): per-row-contiguous global reads + conflict-free
// ds_read_b128 (measured SQ_LDS_BANK_CONFLICT = 0).
// ---------------------------------------------------------------------------
template <typename OutT>
__global__ __launch_bounds__(256)
void gemm_nt(const bf16_t* __restrict__ A, const bf16_t* __restrict__ B,
             OutT* __restrict__ C, int K, int lda, int ldb, int ldc)
{
  const int bm = blockIdx.y, bn = blockIdx.x;
  const int m0 = bm * 128, n0 = bn * 128;

  __shared__ bf16_t As[2][128 * 64];  // 16KB each
  __shared__ bf16_t Bs[2][128 * 64];

  const int tid = threadIdx.x;
  const int wave = tid >> 6, lane = tid & 63;
  const int lm = lane & 15, qd = lane >> 4;
  const int wm = (wave >> 1) * 64, wn = (wave & 1) * 64;

  const int rowl = lane >> 3;           // 0..7
  const int q = (lane & 7) ^ rowl;      // swizzled chunk within row
  const bf16_t* Abase = A + (long)(m0 + wave * 8 + rowl) * lda + q * 8;
  const bf16_t* Bbase = B + (long)(n0 + wave * 8 + rowl) * ldb + q * 8;
  const int woff = wave * 512;

  auto stage = [&](int k0, int b) {
#pragma unroll
    for (int i = 0; i < 4; i++) {
      __builtin_amdgcn_global_load_lds((const AS1 void*)(Abase + (long)i * 32 * lda + k0),
                                       (AS3 void*)(As[b] + woff + i * 2048), 16, 0, 0);
      __builtin_amdgcn_global_load_lds((const AS1 void*)(Bbase + (long)i * 32 * ldb + k0),
                                       (AS3 void*)(Bs[b] + woff + i * 2048), 16, 0, 0);
    }
  };

  f32x4 acc[4][4] = {};

  stage(0, 0);
  int buf = 0;
  for (int k0 = 0; k0 < K; k0 += 64) {
    __syncthreads();                   // drains tile-k loads (issued 1 iter ago)
    if (k0 + 64 < K) stage(k0 + 64, buf ^ 1);
#pragma unroll
    for (int s = 0; s < 2; s++) {
      bf16x8 aF[4], bF[4];
#pragma unroll
      for (int i = 0; i < 4; i++) {
        const int r = wm + i * 16 + lm;
        aF[i] = *(const bf16x8*)&As[buf][r * 64 + (((s * 4 + qd) ^ (lm & 7)) << 3)];
      }
#pragma unroll
      for (int j = 0; j < 4; j++) {
        const int r = wn + j * 16 + lm;
        bF[j] = *(const bf16x8*)&Bs[buf][r * 64 + (((s * 4 + qd) ^ (lm & 7)) << 3)];
      }
#pragma unroll
      for (int i = 0; i < 4; i++)
#pragma unroll
        for (int j = 0; j < 4; j++)
          acc[i][j] = __builtin_amdgcn_mfma_f32_16x16x32_bf16(aF[i], bF[j], acc[i][j], 0, 0, 0);
    }
    buf ^= 1;
  }

#pragma unroll
  for (int i = 0; i < 4; i++) {
    const int row = m0 + wm + i * 16 + qd * 4;
#pragma unroll
    for (int j = 0; j < 4; j++) {
      const int col = n0 + wn + j * 16 + lm;
#pragma unroll
      for (int r = 0; r < 4; r++)
        C[(long)(row + r) * ldc + col] = (OutT)acc[i][j][r];
    }
  }
}

// ---------------------------------------------------------------------------
// Small-tile NT bf16 GEMM for the causal steps: tile 64x128, BK=64,
// 256 threads (wave w covers cols w*32..w*32+31, all 64 rows).
//
// ROUND 9 CHANGE: depth-2 pipeline. rocprof on the dbuf version showed
// MfmaUtil=VALUBusy=13%, HBM 20%, conflicts 0 -> pure latency stall: the
// __syncthreads() drained vmcnt(0) every iter, so tile k+1's loads only got
// the ~200cy compute phase to land against ~600-900cy L2/L3 latency
// (iter time ~1165cy observed vs ~250cy of work).
// Now: TRIPLE-buffered LDS (72KB -> 2 blocks/CU), prologue stages tiles 0+1,
// per iter: sched_barrier | s_waitcnt vmcnt(6) (tile k done, tile k+1 stays
// IN FLIGHT) | raw s_barrier | sched_barrier | stage tile k+2 | compute k.
// Issue-to-use distance ~2 iters; main loop never drains to vmcnt(0) (T3/T4).
// sched_barrier(0) fences both sides of the raw barrier so the scheduler
// cannot sink MFMAs below it or hoist ds_reads above it (race rule #18).
//
// Same XOR-swizzled LDS layout (slot = q ^ (row&7)), measured conflict-free.
//
// causalHalf: skip block if bn > bm>>1    (S = QK^T lower-triangle tiles)
// kLimit64:   Keff = min(K, ((bm>>1)+1)*128), bm flipped heavy-first
//             (PV truncation; row-uniform within a 64-row tile and equal to
//              softmax's zero-filled kend -> no uninitialized P reads).
//             Keff is always a multiple of 128 -> >=2 K-tiles, so the
//             2-tile prologue is always in-bounds.
// ---------------------------------------------------------------------------
template <typename OutT>
__global__ __launch_bounds__(256)
void gemm_nt64(const bf16_t* __restrict__ A, const bf16_t* __restrict__ B,
               OutT* __restrict__ C, int K, int lda, int ldb, int ldc,
               long sA, long sB, long sC, int causalHalf, int kLimit64)
{
  int bm = blockIdx.y;
  const int bn = blockIdx.x;
  if (kLimit64) bm = gridDim.y - 1 - bm;   // heavy tiles dispatch first
  if (causalHalf && bn > (bm >> 1)) return;
  A += (long)blockIdx.z * sA;
  B += (long)blockIdx.z * sB;
  C += (long)blockIdx.z * sC;
  const int m0 = bm * 64, n0 = bn * 128;
  int Keff = K;
  if (kLimit64) { const int kl = ((bm >> 1) + 1) * 128; if (kl < Keff) Keff = kl; }

  __shared__ bf16_t As[3][64 * 64];    // 8KB each
  __shared__ bf16_t Bs[3][128 * 64];   // 16KB each  (72KB total, 2 blocks/CU)

  const int tid = threadIdx.x;
  const int wave = tid >> 6, lane = tid & 63;
  const int lm = lane & 15, qd = lane >> 4;
  const int wn = wave * 32;

  const int rowl = lane >> 3;           // 0..7
  const int q = (lane & 7) ^ rowl;      // swizzled chunk within row
  const bf16_t* Abase = A + (long)(m0 + wave * 8 + rowl) * lda + q * 8;
  const bf16_t* Bbase = B + (long)(n0 + wave * 8 + rowl) * ldb + q * 8;
  const int woff = wave * 512;          // wave-uniform LDS elem base

  // 6 global_load_lds instructions per wave per stage -> vmcnt counts in 6s.
  auto stage = [&](int k0, int b) {
#pragma unroll
    for (int i = 0; i < 2; i++)
      __builtin_amdgcn_global_load_lds((const AS1 void*)(Abase + (long)i * 32 * lda + k0),
                                       (AS3 void*)(As[b] + woff + i * 2048), 16, 0, 0);
#pragma unroll
    for (int i = 0; i < 4; i++)
      __builtin_amdgcn_global_load_lds((const AS1 void*)(Bbase + (long)i * 32 * ldb + k0),
                                       (AS3 void*)(Bs[b] + woff + i * 2048), 16, 0, 0);
  };

  f32x4 acc[4][2] = {};

  stage(0, 0);                          // tile 0 -> buf 0
  stage(64, 1);                         // tile 1 -> buf 1   (12 loads in flight)
  int buf = 0;
  for (int k0 = 0; k0 < Keff; k0 += 64) {
    __builtin_amdgcn_sched_barrier(0);  // nothing sinks below into the wait
    if (k0 + 64 < Keff)
      asm volatile("s_waitcnt vmcnt(6) lgkmcnt(0)" ::: "memory");  // tile k done, k+1 in flight
    else
      asm volatile("s_waitcnt vmcnt(0) lgkmcnt(0)" ::: "memory");  // last tile: full drain
    __builtin_amdgcn_s_barrier();       // raw barrier: no implicit vmcnt(0)
    __builtin_amdgcn_sched_barrier(0);  // nothing hoists above the barrier
    if (k0 + 128 < Keff)
      stage(k0 + 128, buf == 0 ? 2 : buf - 1);   // tile k+2 -> buffer freed last iter
#pragma unroll
    for (int s = 0; s < 2; s++) {
      bf16x8 aF[4], bF[2];
#pragma unroll
      for (int i = 0; i < 4; i++) {
        const int r = i * 16 + lm;
        aF[i] = *(const bf16x8*)&As[buf][r * 64 + (((s * 4 + qd) ^ (lm & 7)) << 3)];
      }
#pragma unroll
      for (int j = 0; j < 2; j++) {
        const int r = wn + j * 16 + lm;
        bF[j] = *(const bf16x8*)&Bs[buf][r * 64 + (((s * 4 + qd) ^ (lm & 7)) << 3)];
      }
#pragma unroll
      for (int i = 0; i < 4; i++)
#pragma unroll
        for (int j = 0; j < 2; j++)
          acc[i][j] = __builtin_amdgcn_mfma_f32_16x16x32_bf16(aF[i], bF[j], acc[i][j], 0, 0, 0);
    }
    buf = (buf == 2) ? 0 : buf + 1;
  }

#pragma unroll
  for (int i = 0; i < 4; i++) {
    const int row = m0 + i * 16 + qd * 4;
#pragma unroll
    for (int j = 0; j < 2; j++) {
      const int col = n0 + wn + j * 16 + lm;
#pragma unroll
      for (int r = 0; r < 4; r++)
        C[(long)(row + r) * ldc + col] = (OutT)acc[i][j][r];
    }
  }
}

// ---------------------------------------------------------------------------
// Fused prep (ONE dispatch): blocks [0,8192) convert X fp32->bf16 (float4
// loads); blocks [8192, 8192+3072) transpose+convert Wq/Wk/Wv into
// WT[out][in] bf16 (32x32 tiles, 256 threads, 4 rows/thread). The 3072
// small transpose blocks backfill the cvt tail.
// ---------------------------------------------------------------------------
__global__ __launch_bounds__(256)
void prep(const float* __restrict__ X, bf16_t* __restrict__ Xb,
          const float* __restrict__ wq, const float* __restrict__ wk,
          const float* __restrict__ wv, bf16_t* __restrict__ WT)
{
  const int b = blockIdx.x;
  if (b < 8192) {                       // X -> bf16, 4 floats/thread
    const int i = b * 256 + threadIdx.x;
    const float4 f = ((const float4*)X)[i];
    bf16x4 o = {(bf16_t)f.x, (bf16_t)f.y, (bf16_t)f.z, (bf16_t)f.w};
    ((bf16x4*)Xb)[i] = o;
    return;
  }
  const int wid = b - 8192;             // 0..3071
  const int z = wid >> 10;              // which W
  const int t = wid & 1023;             // tile id, 32x32 grid of 32x32 tiles
  const int tix = t & 31, tiy = t >> 5; // tix: out-dim tile, tiy: in-dim tile
  const float* W = (z == 0) ? wq : (z == 1) ? wk : wv;
  bf16_t* O = WT + (long)z * 1024 * 1024;

  __shared__ float tile[32][33];
  const int x = threadIdx.x & 31, y0 = threadIdx.x >> 5;  // y0: 0..7
#pragma unroll
  for (int r = 0; r < 4; r++) {         // read: coalesced over out dim (x)
    const int y = y0 + r * 8;
    tile[y][x] = W[(long)(tiy * 32 + y) * 1024 + (tix * 32 + x)];
  }
  __syncthreads();
#pragma unroll
  for (int r = 0; r < 4; r++) {         // write: coalesced over in dim (x)
    const int y = y0 + r * 8;
    O[(long)(tix * 32 + y) * 1024 + (tiy * 32 + x)] = (bf16_t)tile[x][y];
  }
}

// ---------------------------------------------------------------------------
// In-place causal softmax over S rows (bf16, ld=2048). One block per row.
// logits = S/32; writes P = softmax, zeros above the diagonal.
// Loads only j <= t; stores only j < kend = ((t>>7)+1)*128 — beyond kend P
// is never read by the PV GEMM (Keff stops there); [t+1, kend) gets zeros.
// ---------------------------------------------------------------------------
__global__ __launch_bounds__(256)
void softmax_causal(bf16_t* __restrict__ S)
{
  const int row = blockIdx.x;
  const int t = row & 2047;
  const int kend = ((t >> 7) + 1) << 7;
  bf16_t* Sr = S + (long)row * 2048;
  const int base = threadIdx.x * 8;

  uint4 u = {0, 0, 0, 0};
  if (base <= t) u = *(const uint4*)(Sr + base);
  const unsigned short* up = (const unsigned short*)&u;
  float v[8];
  float m = -3.0e38f;
#pragma unroll
  for (int j = 0; j < 8; j++) {
    const float x = __uint_as_float(((unsigned)up[j]) << 16);  // bf16 bits -> f32
    v[j] = (base + j <= t) ? x : -3.0e38f;
    m = fmaxf(m, v[j]);
  }
#pragma unroll
  for (int off = 32; off > 0; off >>= 1) m = fmaxf(m, __shfl_xor(m, off));
  __shared__ float redm[4], redl[4];
  const int wave = threadIdx.x >> 6, lane = threadIdx.x & 63;
  if (lane == 0) redm[wave] = m;
  __syncthreads();
  m = fmaxf(fmaxf(redm[0], redm[1]), fmaxf(redm[2], redm[3]));

  float p[8], l = 0.f;
#pragma unroll
  for (int j = 0; j < 8; j++) {
    p[j] = (base + j <= t) ? __expf((v[j] - m) * 0.03125f) : 0.f;
    l += p[j];
  }
#pragma unroll
  for (int off = 32; off > 0; off >>= 1) l += __shfl_xor(l, off);
  if (lane == 0) redl[wave] = l;
  __syncthreads();
  l = (redl[0] + redl[1]) + (redl[2] + redl[3]);
  const float rl = 1.0f / l;

  if (base < kend) {
    uint4 w;
    unsigned* wp = (unsigned*)&w;
#pragma unroll
    for (int h = 0; h < 4; h++) {
      bf16_t a = (bf16_t)(p[2 * h] * rl);
      bf16_t b = (bf16_t)(p[2 * h + 1] * rl);
      wp[h] = (unsigned)__builtin_bit_cast(unsigned short, a) |
              ((unsigned)__builtin_bit_cast(unsigned short, b) << 16);
    }
    *(uint4*)(Sr + base) = w;
  }
}

// ---------------------------------------------------------------------------
extern "C" void kernel_launch(void* const* d_in, const int* in_sizes, int n_in,
                              void* d_out, int out_size, void* d_ws, size_t ws_size,
                              hipStream_t stream)
{
  const float* X  = (const float*)d_in[0];  // [4,2048,1024]
  const float* Wq = (const float*)d_in[1];  // [1024,1024] (in,out)
  const float* Wk = (const float*)d_in[2];
  const float* Wv = (const float*)d_in[3];
  float* out = (float*)d_out;               // [4,2048,1024]

  // workspace layout (bytes): QK 33.5M | VT 16.8M | WT 6.3M | {Xb 16.8M / S 33.5M overlap}
  char* p = (char*)d_ws;
  bf16_t* QK = (bf16_t*)p;  p += (size_t)8192 * 2048 * 2;   // [8192, 2048]  Q|K
  bf16_t* VT = (bf16_t*)p;  p += (size_t)1024 * 8192 * 2;   // [1024, 8192]  V^T
  bf16_t* WT = (bf16_t*)p;  p += (size_t)3072 * 1024 * 2;   // [3072, 1024]  Wq^T|Wk^T|Wv^T
  bf16_t* Xb = (bf16_t*)p;                                  // [8192, 1024]  (dead before S)
  bf16_t* S  = (bf16_t*)p;                                  // [4][2048,2048] scores->P

  // 1) fused prep: X -> bf16  +  W -> WT (bf16, transposed)   (one dispatch)
  prep<<<8192 + 3072, 256, 0, stream>>>(X, Xb, Wq, Wk, Wv, WT);
  // 2) QK = Xb @ [Wq|Wk]   M=8192 N=2048 K=1024   (1024 blocks, dbuf)
  gemm_nt<bf16_t><<<dim3(16, 64), 256, 0, stream>>>(
      Xb, WT, QK, 1024, 1024, 1024, 2048);
  // 3) VT = WvT @ Xb^T     M=1024 N=8192 K=1024   (512 blocks, dbuf)
  gemm_nt<bf16_t><<<dim3(64, 8), 256, 0, stream>>>(
      WT + (long)2048 * 1024, Xb, VT, 1024, 1024, 1024, 8192);
  // 4) S = Q @ K^T per batch, 64-row tiles, lower-tri only (1088 active), depth-2 pipe
  gemm_nt64<bf16_t><<<dim3(16, 32, 4), 256, 0, stream>>>(
      QK, QK + 1024, S, 1024, 2048, 2048, 2048,
      (long)2048 * 2048, (long)2048 * 2048, (long)2048 * 2048, 1, 0);
  // 5) in-place causal softmax (truncated IO)
  softmax_causal<<<8192, 256, 0, stream>>>(S);
  // 6) O = P @ V (NT vs V^T), 64-row tiles, K truncated at diagonal, depth-2 pipe
  gemm_nt64<float><<<dim3(8, 32, 4), 256, 0, stream>>>(
      S, VT, out, 2048, 2048, 8192, 1024,
      (long)2048 * 2048, 2048, (long)2048 * 1024, 0, 1);
}

// Round 2
// 248.659 us; speedup vs baseline: 1.0828x; 1.0828x over previous
//
#include <hip/hip_runtime.h>
#include <cstdint>

typedef __bf16 bf16_t;
typedef __attribute__((ext_vector_type(8))) __bf16 bf16x8;
typedef __attribute__((ext_vector_type(4))) __bf16 bf16x4;
typedef __attribute__((ext_vector_type(4))) float f32x4;

#define AS1 __attribute__((address_space(1)))
#define AS3 __attribute__((address_space(3)))

// ---------------------------------------------------------------------------
// Big-tile NT bf16 GEMM: C[m,n] = sum_k A[m*lda+k] * B[n*ldb+k]
// Tile 128x128, BK=64, 256 threads, DOUBLE-BUFFERED LDS (64KB, 2 blocks/CU).
// One barrier/iter; prefetch for tile k+1 issued right after it. 717 TF
// measured (round 7, step 3). DO NOT merge multiple operand sets into this
// kernel (round 8: VGPR 88->132, MfmaUtil 28->20.5, -33% perf).
//
// ROUND 9 post-mortem: depth-2 pipeline on the 64-row kernel REGRESSED
// (50->62.6us, MfmaUtil 13->10.7) tracking occupancy 3->2 blocks/CU. So the
// causal steps are BANDWIDTH-bound (L2/L3 delivery ~9 TB/s), not
// latency-bound. Fix: raise arithmetic intensity instead -> causal steps now
// use this 128x128 tile (AI 64 vs 42.7 FLOP/B) via gemm_ntc below.
//
// LDS layout: rows of 8 16B-chunks, chunk q of row r at slot q ^ (r&7)
// (XOR swizzle): per-row-contiguous global reads + conflict-free
// ds_read_b128 (measured SQ_LDS_BANK_CONFLICT = 0).
// ---------------------------------------------------------------------------
template <typename OutT>
__global__ __launch_bounds__(256)
void gemm_nt(const bf16_t* __restrict__ A, const bf16_t* __restrict__ B,
             OutT* __restrict__ C, int K, int lda, int ldb, int ldc)
{
  const int bm = blockIdx.y, bn = blockIdx.x;
  const int m0 = bm * 128, n0 = bn * 128;

  __shared__ bf16_t As[2][128 * 64];  // 16KB each
  __shared__ bf16_t Bs[2][128 * 64];

  const int tid = threadIdx.x;
  const int wave = tid >> 6, lane = tid & 63;
  const int lm = lane & 15, qd = lane >> 4;
  const int wm = (wave >> 1) * 64, wn = (wave & 1) * 64;

  const int rowl = lane >> 3;           // 0..7
  const int q = (lane & 7) ^ rowl;      // swizzled chunk within row
  const bf16_t* Abase = A + (long)(m0 + wave * 8 + rowl) * lda + q * 8;
  const bf16_t* Bbase = B + (long)(n0 + wave * 8 + rowl) * ldb + q * 8;
  const int woff = wave * 512;

  auto stage = [&](int k0, int b) {
#pragma unroll
    for (int i = 0; i < 4; i++) {
      __builtin_amdgcn_global_load_lds((const AS1 void*)(Abase + (long)i * 32 * lda + k0),
                                       (AS3 void*)(As[b] + woff + i * 2048), 16, 0, 0);
      __builtin_amdgcn_global_load_lds((const AS1 void*)(Bbase + (long)i * 32 * ldb + k0),
                                       (AS3 void*)(Bs[b] + woff + i * 2048), 16, 0, 0);
    }
  };

  f32x4 acc[4][4] = {};

  stage(0, 0);
  int buf = 0;
  for (int k0 = 0; k0 < K; k0 += 64) {
    __syncthreads();                   // drains tile-k loads (issued 1 iter ago)
    if (k0 + 64 < K) stage(k0 + 64, buf ^ 1);
#pragma unroll
    for (int s = 0; s < 2; s++) {
      bf16x8 aF[4], bF[4];
#pragma unroll
      for (int i = 0; i < 4; i++) {
        const int r = wm + i * 16 + lm;
        aF[i] = *(const bf16x8*)&As[buf][r * 64 + (((s * 4 + qd) ^ (lm & 7)) << 3)];
      }
#pragma unroll
      for (int j = 0; j < 4; j++) {
        const int r = wn + j * 16 + lm;
        bF[j] = *(const bf16x8*)&Bs[buf][r * 64 + (((s * 4 + qd) ^ (lm & 7)) << 3)];
      }
#pragma unroll
      for (int i = 0; i < 4; i++)
#pragma unroll
        for (int j = 0; j < 4; j++)
          acc[i][j] = __builtin_amdgcn_mfma_f32_16x16x32_bf16(aF[i], bF[j], acc[i][j], 0, 0, 0);
    }
    buf ^= 1;
  }

#pragma unroll
  for (int i = 0; i < 4; i++) {
    const int row = m0 + wm + i * 16 + qd * 4;
#pragma unroll
    for (int j = 0; j < 4; j++) {
      const int col = n0 + wn + j * 16 + lm;
#pragma unroll
      for (int r = 0; r < 4; r++)
        C[(long)(row + r) * ldc + col] = (OutT)acc[i][j][r];
    }
  }
}

// ---------------------------------------------------------------------------
// Causal 128x128 NT GEMM — identical structure to gemm_nt (same dbuf, same
// swizzle, same 64KB LDS, one __syncthreads/iter) plus batch strides and two
// causal modes. Kept as a SEPARATE kernel so steps 2/3 codegen is untouched.
//
// causal=1:  skip block if bn > bm (S = QK^T lower-triangle 128-tiles).
//            Diagonal blocks compute their upper triangle as garbage; softmax
//            never reads j > t and zero-fills [t+1, kend) -> safe.
// kLimit=1:  Keff = min(K, (bm+1)*128), bm flipped heavy-first. Row-uniform
//            for 128-row tiles (kend = ((t>>7)+1)*128) and equal to softmax's
//            zero-filled region -> no uninitialized P reads in PV.
//            Keff is a multiple of 128 -> >= 2 K-iters, prologue in-bounds.
// ---------------------------------------------------------------------------
template <typename OutT>
__global__ __launch_bounds__(256)
void gemm_ntc(const bf16_t* __restrict__ A, const bf16_t* __restrict__ B,
              OutT* __restrict__ C, int K, int lda, int ldb, int ldc,
              long sA, long sB, long sC, int causal, int kLimit)
{
  int bm = blockIdx.y;
  const int bn = blockIdx.x;
  if (kLimit) bm = gridDim.y - 1 - bm;   // heavy tiles dispatch first
  if (causal && bn > bm) return;
  A += (long)blockIdx.z * sA;
  B += (long)blockIdx.z * sB;
  C += (long)blockIdx.z * sC;
  const int m0 = bm * 128, n0 = bn * 128;
  int Keff = K;
  if (kLimit) { const int kl = (bm + 1) * 128; if (kl < Keff) Keff = kl; }

  __shared__ bf16_t As[2][128 * 64];  // 16KB each
  __shared__ bf16_t Bs[2][128 * 64];

  const int tid = threadIdx.x;
  const int wave = tid >> 6, lane = tid & 63;
  const int lm = lane & 15, qd = lane >> 4;
  const int wm = (wave >> 1) * 64, wn = (wave & 1) * 64;

  const int rowl = lane >> 3;           // 0..7
  const int q = (lane & 7) ^ rowl;      // swizzled chunk within row
  const bf16_t* Abase = A + (long)(m0 + wave * 8 + rowl) * lda + q * 8;
  const bf16_t* Bbase = B + (long)(n0 + wave * 8 + rowl) * ldb + q * 8;
  const int woff = wave * 512;

  auto stage = [&](int k0, int b) {
#pragma unroll
    for (int i = 0; i < 4; i++) {
      __builtin_amdgcn_global_load_lds((const AS1 void*)(Abase + (long)i * 32 * lda + k0),
                                       (AS3 void*)(As[b] + woff + i * 2048), 16, 0, 0);
      __builtin_amdgcn_global_load_lds((const AS1 void*)(Bbase + (long)i * 32 * ldb + k0),
                                       (AS3 void*)(Bs[b] + woff + i * 2048), 16, 0, 0);
    }
  };

  f32x4 acc[4][4] = {};

  stage(0, 0);
  int buf = 0;
  for (int k0 = 0; k0 < Keff; k0 += 64) {
    __syncthreads();                   // drains tile-k loads (issued 1 iter ago)
    if (k0 + 64 < Keff) stage(k0 + 64, buf ^ 1);
#pragma unroll
    for (int s = 0; s < 2; s++) {
      bf16x8 aF[4], bF[4];
#pragma unroll
      for (int i = 0; i < 4; i++) {
        const int r = wm + i * 16 + lm;
        aF[i] = *(const bf16x8*)&As[buf][r * 64 + (((s * 4 + qd) ^ (lm & 7)) << 3)];
      }
#pragma unroll
      for (int j = 0; j < 4; j++) {
        const int r = wn + j * 16 + lm;
        bF[j] = *(const bf16x8*)&Bs[buf][r * 64 + (((s * 4 + qd) ^ (lm & 7)) << 3)];
      }
#pragma unroll
      for (int i = 0; i < 4; i++)
#pragma unroll
        for (int j = 0; j < 4; j++)
          acc[i][j] = __builtin_amdgcn_mfma_f32_16x16x32_bf16(aF[i], bF[j], acc[i][j], 0, 0, 0);
    }
    buf ^= 1;
  }

#pragma unroll
  for (int i = 0; i < 4; i++) {
    const int row = m0 + wm + i * 16 + qd * 4;
#pragma unroll
    for (int j = 0; j < 4; j++) {
      const int col = n0 + wn + j * 16 + lm;
#pragma unroll
      for (int r = 0; r < 4; r++)
        C[(long)(row + r) * ldc + col] = (OutT)acc[i][j][r];
    }
  }
}

// ---------------------------------------------------------------------------
// Fused prep (ONE dispatch): blocks [0,8192) convert X fp32->bf16 (float4
// loads); blocks [8192, 8192+3072) transpose+convert Wq/Wk/Wv into
// WT[out][in] bf16 (32x32 tiles, 256 threads, 4 rows/thread). The 3072
// small transpose blocks backfill the cvt tail.
// ---------------------------------------------------------------------------
__global__ __launch_bounds__(256)
void prep(const float* __restrict__ X, bf16_t* __restrict__ Xb,
          const float* __restrict__ wq, const float* __restrict__ wk,
          const float* __restrict__ wv, bf16_t* __restrict__ WT)
{
  const int b = blockIdx.x;
  if (b < 8192) {                       // X -> bf16, 4 floats/thread
    const int i = b * 256 + threadIdx.x;
    const float4 f = ((const float4*)X)[i];
    bf16x4 o = {(bf16_t)f.x, (bf16_t)f.y, (bf16_t)f.z, (bf16_t)f.w};
    ((bf16x4*)Xb)[i] = o;
    return;
  }
  const int wid = b - 8192;             // 0..3071
  const int z = wid >> 10;              // which W
  const int t = wid & 1023;             // tile id, 32x32 grid of 32x32 tiles
  const int tix = t & 31, tiy = t >> 5; // tix: out-dim tile, tiy: in-dim tile
  const float* W = (z == 0) ? wq : (z == 1) ? wk : wv;
  bf16_t* O = WT + (long)z * 1024 * 1024;

  __shared__ float tile[32][33];
  const int x = threadIdx.x & 31, y0 = threadIdx.x >> 5;  // y0: 0..7
#pragma unroll
  for (int r = 0; r < 4; r++) {         // read: coalesced over out dim (x)
    const int y = y0 + r * 8;
    tile[y][x] = W[(long)(tiy * 32 + y) * 1024 + (tix * 32 + x)];
  }
  __syncthreads();
#pragma unroll
  for (int r = 0; r < 4; r++) {         // write: coalesced over in dim (x)
    const int y = y0 + r * 8;
    O[(long)(tix * 32 + y) * 1024 + (tiy * 32 + x)] = (bf16_t)tile[x][y];
  }
}

// ---------------------------------------------------------------------------
// In-place causal softmax over S rows (bf16, ld=2048). One block per row.
// logits = S/32; writes P = softmax, zeros above the diagonal.
// Loads only j <= t; stores only j < kend = ((t>>7)+1)*128 — beyond kend P
// is never read by the PV GEMM (Keff stops there); [t+1, kend) gets zeros.
// ---------------------------------------------------------------------------
__global__ __launch_bounds__(256)
void softmax_causal(bf16_t* __restrict__ S)
{
  const int row = blockIdx.x;
  const int t = row & 2047;
  const int kend = ((t >> 7) + 1) << 7;
  bf16_t* Sr = S + (long)row * 2048;
  const int base = threadIdx.x * 8;

  uint4 u = {0, 0, 0, 0};
  if (base <= t) u = *(const uint4*)(Sr + base);
  const unsigned short* up = (const unsigned short*)&u;
  float v[8];
  float m = -3.0e38f;
#pragma unroll
  for (int j = 0; j < 8; j++) {
    const float x = __uint_as_float(((unsigned)up[j]) << 16);  // bf16 bits -> f32
    v[j] = (base + j <= t) ? x : -3.0e38f;
    m = fmaxf(m, v[j]);
  }
#pragma unroll
  for (int off = 32; off > 0; off >>= 1) m = fmaxf(m, __shfl_xor(m, off));
  __shared__ float redm[4], redl[4];
  const int wave = threadIdx.x >> 6, lane = threadIdx.x & 63;
  if (lane == 0) redm[wave] = m;
  __syncthreads();
  m = fmaxf(fmaxf(redm[0], redm[1]), fmaxf(redm[2], redm[3]));

  float p[8], l = 0.f;
#pragma unroll
  for (int j = 0; j < 8; j++) {
    p[j] = (base + j <= t) ? __expf((v[j] - m) * 0.03125f) : 0.f;
    l += p[j];
  }
#pragma unroll
  for (int off = 32; off > 0; off >>= 1) l += __shfl_xor(l, off);
  if (lane == 0) redl[wave] = l;
  __syncthreads();
  l = (redl[0] + redl[1]) + (redl[2] + redl[3]);
  const float rl = 1.0f / l;

  if (base < kend) {
    uint4 w;
    unsigned* wp = (unsigned*)&w;
#pragma unroll
    for (int h = 0; h < 4; h++) {
      bf16_t a = (bf16_t)(p[2 * h] * rl);
      bf16_t b = (bf16_t)(p[2 * h + 1] * rl);
      wp[h] = (unsigned)__builtin_bit_cast(unsigned short, a) |
              ((unsigned)__builtin_bit_cast(unsigned short, b) << 16);
    }
    *(uint4*)(Sr + base) = w;
  }
}

// ---------------------------------------------------------------------------
extern "C" void kernel_launch(void* const* d_in, const int* in_sizes, int n_in,
                              void* d_out, int out_size, void* d_ws, size_t ws_size,
                              hipStream_t stream)
{
  const float* X  = (const float*)d_in[0];  // [4,2048,1024]
  const float* Wq = (const float*)d_in[1];  // [1024,1024] (in,out)
  const float* Wk = (const float*)d_in[2];
  const float* Wv = (const float*)d_in[3];
  float* out = (float*)d_out;               // [4,2048,1024]

  // workspace layout (bytes): QK 33.5M | VT 16.8M | WT 6.3M | {Xb 16.8M / S 33.5M overlap}
  char* p = (char*)d_ws;
  bf16_t* QK = (bf16_t*)p;  p += (size_t)8192 * 2048 * 2;   // [8192, 2048]  Q|K
  bf16_t* VT = (bf16_t*)p;  p += (size_t)1024 * 8192 * 2;   // [1024, 8192]  V^T
  bf16_t* WT = (bf16_t*)p;  p += (size_t)3072 * 1024 * 2;   // [3072, 1024]  Wq^T|Wk^T|Wv^T
  bf16_t* Xb = (bf16_t*)p;                                  // [8192, 1024]  (dead before S)
  bf16_t* S  = (bf16_t*)p;                                  // [4][2048,2048] scores->P

  // 1) fused prep: X -> bf16  +  W -> WT (bf16, transposed)   (one dispatch)
  prep<<<8192 + 3072, 256, 0, stream>>>(X, Xb, Wq, Wk, Wv, WT);
  // 2) QK = Xb @ [Wq|Wk]   M=8192 N=2048 K=1024   (1024 blocks, dbuf)
  gemm_nt<bf16_t><<<dim3(16, 64), 256, 0, stream>>>(
      Xb, WT, QK, 1024, 1024, 1024, 2048);
  // 3) VT = WvT @ Xb^T     M=1024 N=8192 K=1024   (512 blocks, dbuf)
  gemm_nt<bf16_t><<<dim3(64, 8), 256, 0, stream>>>(
      WT + (long)2048 * 1024, Xb, VT, 1024, 1024, 1024, 8192);
  // 4) S = Q @ K^T per batch, 128x128 lower-tri tiles (544 active), dbuf
  gemm_ntc<bf16_t><<<dim3(16, 16, 4), 256, 0, stream>>>(
      QK, QK + 1024, S, 1024, 2048, 2048, 2048,
      (long)2048 * 2048, (long)2048 * 2048, (long)2048 * 2048, 1, 0);
  // 5) in-place causal softmax (truncated IO)
  softmax_causal<<<8192, 256, 0, stream>>>(S);
  // 6) O = P @ V (NT vs V^T), 128-row tiles, Keff=(bm+1)*128, heavy-first, dbuf
  gemm_ntc<float><<<dim3(8, 16, 4), 256, 0, stream>>>(
      S, VT, out, 2048, 2048, 8192, 1024,
      (long)2048 * 2048, 2048, (long)2048 * 1024, 0, 1);
}